// Round 9
// baseline (865.005 us; speedup 1.0000x reference)
//
#include <hip/hip_runtime.h>
#include <hip/hip_bf16.h>
#include <stdint.h>

#define KDIM    256
#define NWORDS  1564         // sign words per column
#define NW      1563         // crossing words (ceil(99999/64))

typedef float  f32x4  __attribute__((ext_vector_type(4)));
typedef __bf16 bf16x8 __attribute__((ext_vector_type(8)));

__device__ __forceinline__ void gl_lds16(const void* g, void* l) {
    __builtin_amdgcn_global_load_lds(
        (const __attribute__((address_space(1))) unsigned int*)g,
        (__attribute__((address_space(3))) unsigned int*)l, 16, 0, 0);
}

// ---------- K0: build W, tile-major + read-swizzle pre-applied ----------
__global__ void build_w(const float* __restrict__ theta,
                        const float* __restrict__ noise,
                        __bf16* __restrict__ Wt) {
    int idx = blockIdx.x * 256 + threadIdx.x;   // 0..262143
    int j = idx >> 9;
    int d = idx & 511;
    float v;
    if (j < KDIM) v = theta[j * 512 + d];
    else          v = theta[(j - KDIM) * 512 + d] + 0.01f * noise[(j - KDIM) * 512 + d];
    int t  = d >> 5;
    int g  = (d >> 3) & 3;
    int e  = d & 7;
    int gs = g ^ ((j >> 1) & 3);
    Wt[(((t << 9) + j) << 5) + (gs << 3) + e] = (__bf16)v;
}

// ---------- K1 ablation probe family (R8 structure) ----------
// V0: full (REAL output). V1: no B-DMA. V3: no MFMA (reads asm-live).
// V4: barrier+MFMA only (no memory). V5: full, grid 782, 2 bn-panels/block.
template<int V>
__global__ void __launch_bounds__(512, 4)
gemm_probe(const float* __restrict__ basis,
           const __bf16* __restrict__ Wt,
           uint64_t* __restrict__ outw) {
    constexpr bool HAS_A  = (V != 2 && V != 4);
    constexpr bool HAS_B  = (V != 1 && V != 4);
    constexpr bool HAS_MM = (V != 3);
    constexpr bool HAS_DS = (V != 4);
    constexpr int  REP    = (V == 4 ? 6 : 2);
    constexpr int  NBN    = (V == 5 ? 2 : 1);

    __shared__ char smem[49152];   // A: [2][128r][64B] @0; B: [2][16KB] @16384

    const int tid    = threadIdx.x;
    const int lane   = tid & 63;
    const int wave   = tid >> 6;
    const int wr     = wave >> 2;
    const int wc     = wave & 3;
    const int lane16 = lane & 15;
    const int lgrp   = lane >> 4;

    int bn = 0, bm;
    if constexpr (V == 5) {        // grid 782: bijective (782 = 8*97+6)
        const int orig = blockIdx.x, x = orig & 7;
        bm = (x < 6 ? x * 98 : 588 + (x - 6) * 97) + (orig >> 3);
    } else {                       // grid 1564: bijective (1564 = 8*195+4)
        const int orig = blockIdx.x, x = orig & 7;
        const int wgid = (x < 4 ? x * 196 : 784 + (x - 4) * 195) + (orig >> 3);
        bn = wgid & 1; bm = wgid >> 1;
    }

    const int ar = tid >> 2;
    const int ah = tid & 3;
    int arg = bm * 128 + ar; if (arg > 99999) arg = 99999;
    const float* abase_g = basis + (size_t)arg * 512 + ah * 8;
    const int awofs = ar * 64 + ((ah ^ (ar & 3)) << 4);

    float4 ra[2][2];
    auto cvt_write_A = [&](int slot, int q) {
        bf16x8 a8;
        a8[0] = (__bf16)ra[slot][0].x; a8[1] = (__bf16)ra[slot][0].y;
        a8[2] = (__bf16)ra[slot][0].z; a8[3] = (__bf16)ra[slot][0].w;
        a8[4] = (__bf16)ra[slot][1].x; a8[5] = (__bf16)ra[slot][1].y;
        a8[6] = (__bf16)ra[slot][1].z; a8[7] = (__bf16)ra[slot][1].w;
        *(bf16x8*)(smem + (q << 13) + awofs) = a8;
    };

    bf16x8 af4[4], bf4[4];          // V4 seed fragments (reg-only)
    if constexpr (V == 4) {
        #pragma unroll
        for (int m = 0; m < 4; ++m) {
            uint4 s; s.x = tid * 2654435761u + m; s.y = s.x ^ 0x9e3779b9u;
            s.z = s.x * 3u + 1u; s.w = s.x * 5u + 7u;
            af4[m] = *(bf16x8*)&s;
            uint4 t2; t2.x = s.y + m; t2.y = s.z; t2.z = s.w; t2.w = s.x;
            bf4[m] = *(bf16x8*)&t2;
        }
    }

    for (int rep = 0; rep < REP; ++rep)
    for (int bnn = 0; bnn < NBN; ++bnn) {
        const int bnc = (V == 5) ? bnn : bn;
        const char* bpanel = (const char*)Wt + ((size_t)bnc << 14)
                             + wave * 2048 + lane * 16;
        auto stage_B = [&](int t) {
            char* bdst = smem + 16384 + ((t & 1) << 14) + wave * 2048;
            const char* src = bpanel + ((size_t)t << 15);
            gl_lds16(src,        bdst);
            gl_lds16(src + 1024, bdst + 1024);
        };

        f32x4 acc[4][4] = {};

        // ---- prologue ----
        if constexpr (HAS_A) {
            ra[0][0] = *(const float4*)(abase_g);
            ra[0][1] = *(const float4*)(abase_g + 4);
            ra[1][0] = *(const float4*)(abase_g + 32);
            ra[1][1] = *(const float4*)(abase_g + 36);
        }
        if constexpr (HAS_B) stage_B(0);
        if constexpr (HAS_A && HAS_B) asm volatile("s_waitcnt vmcnt(4)" ::: "memory");
        else if constexpr (HAS_A)     asm volatile("s_waitcnt vmcnt(2)" ::: "memory");
        if constexpr (HAS_A) {
            cvt_write_A(0, 0);
            asm volatile("s_waitcnt lgkmcnt(0)" ::: "memory");
        }

        #pragma unroll
        for (int t = 0; t < 16; ++t) {
            if constexpr (HAS_A) {
                if (t < 14) {
                    ra[t & 1][0] = *(const float4*)(abase_g + (t + 2) * 32);
                    ra[t & 1][1] = *(const float4*)(abase_g + (t + 2) * 32 + 4);
                }
            }
            if constexpr (V == 4) {
                asm volatile("s_barrier" ::: "memory");
            } else if constexpr (V == 2) {
                asm volatile("s_waitcnt vmcnt(0)\ns_barrier" ::: "memory");
            } else {
                if (t < 14) asm volatile("s_waitcnt vmcnt(2)\ns_barrier" ::: "memory");
                else        asm volatile("s_waitcnt vmcnt(0)\ns_barrier" ::: "memory");
            }
            if constexpr (HAS_B) { if (t < 15) stage_B(t + 1); }

            const char* ab = smem + ((t & 1) << 13);
            const char* bb = smem + 16384 + ((t & 1) << 14);

            bf16x8 afv[4], bfv[4];
            if constexpr (HAS_DS) {
                #pragma unroll
                for (int n = 0; n < 4; ++n) {
                    int cc = wc * 64 + n * 16 + lane16;
                    if constexpr (V == 1)
                        bfv[n] = *(const bf16x8*)(ab + (cc & 127) * 64
                                   + ((lgrp ^ ((cc >> 1) & 3)) << 4));
                    else
                        bfv[n] = *(const bf16x8*)(bb + cc * 64
                                   + ((lgrp ^ ((cc >> 1) & 3)) << 4));
                }
                #pragma unroll
                for (int m = 0; m < 4; ++m) {
                    int rr = wr * 64 + m * 16 + lane16;
                    if constexpr (V == 2)
                        afv[m] = *(const bf16x8*)(bb + rr * 64 + ((lgrp ^ (rr & 3)) << 4));
                    else
                        afv[m] = *(const bf16x8*)(ab + rr * 64 + ((lgrp ^ (rr & 3)) << 4));
                }
                asm volatile("s_waitcnt lgkmcnt(0)" ::: "memory");
                __builtin_amdgcn_sched_barrier(0);
            }

            if constexpr (HAS_MM) {
                __builtin_amdgcn_s_setprio(1);
                #pragma unroll
                for (int m = 0; m < 4; ++m)
                    #pragma unroll
                    for (int n = 0; n < 4; ++n) {
                        if constexpr (HAS_DS)
                            acc[m][n] = __builtin_amdgcn_mfma_f32_16x16x32_bf16(
                                afv[m], bfv[n], acc[m][n], 0, 0, 0);
                        else
                            acc[m][n] = __builtin_amdgcn_mfma_f32_16x16x32_bf16(
                                af4[m], bf4[n], acc[m][n], 0, 0, 0);
                    }
                __builtin_amdgcn_s_setprio(0);
            } else {
                // keep full b128 reads live (rule 17); tiny acc update keeps
                // epilogue unfoldable
                #pragma unroll
                for (int m = 0; m < 4; ++m) {
                    uint4 u = *(uint4*)&afv[m];
                    asm volatile("" :: "v"(u.x), "v"(u.y), "v"(u.z), "v"(u.w));
                    acc[m][0][0] += (float)afv[m][0];
                }
                #pragma unroll
                for (int n = 0; n < 4; ++n) {
                    uint4 u = *(uint4*)&bfv[n];
                    asm volatile("" :: "v"(u.x), "v"(u.y), "v"(u.z), "v"(u.w));
                    acc[0][n][1] += (float)bfv[n][0];
                }
            }

            if constexpr (HAS_A) {
                if (t < 15) {
                    cvt_write_A((t + 1) & 1, (t + 1) & 1);
                    asm volatile("s_waitcnt lgkmcnt(0)" ::: "memory");
                }
            }
        }

        // ---- epilogue: sign pack -> u64 words ----
        asm volatile("s_barrier" ::: "memory");
        unsigned char* sb = (unsigned char*)smem;     // [256 cols][136B]
        #pragma unroll
        for (int m = 0; m < 4; ++m) {
            #pragma unroll
            for (int n = 0; n < 4; ++n) {
                int cc = wc * 64 + n * 16 + lane16;
                int rb = wr * 64 + m * 16 + lgrp * 4;
                uint32_t pk = 0;
                #pragma unroll
                for (int r = 0; r < 4; ++r)
                    pk |= (acc[m][n][r] < 0.0f ? 1u : 0u) << (8 * r);
                *(uint32_t*)&sb[cc * 136 + rb] = pk;
            }
        }
        asm volatile("s_waitcnt lgkmcnt(0)\ns_barrier" ::: "memory");
        {
            const int col = tid & 255;
            const int wh  = tid >> 8;
            const unsigned char* src = &sb[col * 136 + wh * 64];
            uint64_t wbits = 0;
            #pragma unroll
            for (int k = 0; k < 16; ++k) {
                uint32_t qv = *(const uint32_t*)&src[4 * k];
                uint32_t p4 = ((qv & 0x01010101u) * 0x10204080u) >> 28;
                wbits |= (uint64_t)p4 << (4 * k);
            }
            outw[(size_t)(bm * 2 + wh) * 512 + bnc * 256 + col] = wbits;
        }
        asm volatile("s_waitcnt lgkmcnt(0)\ns_barrier" ::: "memory");  // reuse guard
    }
}

// ---------- K2: crossing masks from sign bits ----------
__global__ void crossing_masks(const uint64_t* __restrict__ sbits,
                               uint64_t* __restrict__ maskT) {
    const int w = blockIdx.x;
    const int j = threadIdx.x;
    uint64_t s0r = sbits[(size_t)w * 512 + j];
    uint64_t s0p = sbits[(size_t)w * 512 + 256 + j];
    uint64_t s1r = sbits[(size_t)(w + 1) * 512 + j];
    uint64_t s1p = sbits[(size_t)(w + 1) * 512 + 256 + j];
    uint64_t cr = s0r ^ ((s0r >> 1) | (s1r << 63));
    uint64_t cp = s0p ^ ((s0p >> 1) | (s1p << 63));
    uint64_t m = cr & cp;
    if (w == NW - 1) m &= 0x7FFFFFFFull;
    maskT[(size_t)w * 256 + j] = m;
}

// ---------- K3: pairwise AND-popcount ----------
__global__ void zero_out(float* __restrict__ out) {
    int i = blockIdx.x * 256 + threadIdx.x;
    if (i < 32640) out[i] = 0.0f;
}

__global__ void pair_popcount(const uint64_t* __restrict__ maskT,
                              float* __restrict__ out) {
    const int i = blockIdx.x;
    const int c = blockIdx.y;
    const int j = threadIdx.x;
    if (j <= i) return;
    int w0 = c * 196;
    int w1 = w0 + 196; if (w1 > NW) w1 = NW;
    uint32_t sum = 0;
    #pragma unroll 4
    for (int w = w0; w < w1; ++w) {
        uint64_t mi = maskT[(size_t)w * 256 + i];
        uint64_t mj = maskT[(size_t)w * 256 + j];
        sum += (uint32_t)__popcll(mi & mj);
    }
    const size_t idx = (size_t)i * (2 * KDIM - i - 1) / 2 + (size_t)(j - i - 1);
    atomicAdd(&out[idx], (float)sum);
}

extern "C" void kernel_launch(void* const* d_in, const int* in_sizes, int n_in,
                              void* d_out, int out_size, void* d_ws, size_t ws_size,
                              hipStream_t stream) {
    const float* theta = (const float*)d_in[0];
    const float* basis = (const float*)d_in[1];
    const float* noise = (const float*)d_in[2];
    float* out = (float*)d_out;

    char* ws = (char*)d_ws;
    __bf16*   Wt    = (__bf16*)ws;                              // 512 KB
    uint64_t* sbits = (uint64_t*)(ws + 524288);                 // 6.41 MB
    uint64_t* maskT = (uint64_t*)(ws + 524288 + (size_t)NWORDS * 512 * 8);
    uint64_t* scr   = (uint64_t*)(ws + (16u << 20));            // probe scratch

    hipLaunchKernelGGL(build_w,        dim3(1024),    dim3(256), 0, stream, theta, noise, Wt);
    hipLaunchKernelGGL((gemm_probe<0>), dim3(1564),   dim3(512), 0, stream, basis, Wt, sbits);
    hipLaunchKernelGGL((gemm_probe<1>), dim3(1564),   dim3(512), 0, stream, basis, Wt, scr);
    hipLaunchKernelGGL((gemm_probe<3>), dim3(1564),   dim3(512), 0, stream, basis, Wt, scr);
    hipLaunchKernelGGL((gemm_probe<4>), dim3(1564),   dim3(512), 0, stream, basis, Wt, scr);
    hipLaunchKernelGGL((gemm_probe<5>), dim3(782),    dim3(512), 0, stream, basis, Wt, scr);
    hipLaunchKernelGGL(crossing_masks, dim3(NW),      dim3(256), 0, stream, sbits, maskT);
    hipLaunchKernelGGL(zero_out,       dim3(128),     dim3(256), 0, stream, out);
    hipLaunchKernelGGL(pair_popcount,  dim3(KDIM, 8), dim3(256), 0, stream, maskT, out);
}

// Round 10
// 122.506 us; speedup vs baseline: 7.0609x; 7.0609x over previous
//
#include <hip/hip_runtime.h>
#include <hip/hip_bf16.h>
#include <stdint.h>

#define KDIM    256
#define NWORDS  1564         // sign words per column (= gemm grid: 64-row stripes)
#define NW      1563         // crossing words (ceil(99999/64))

typedef float  f32x4  __attribute__((ext_vector_type(4)));
typedef __bf16 bf16x8 __attribute__((ext_vector_type(8)));
typedef __bf16 bf16x4 __attribute__((ext_vector_type(4)));

// ---------- K0: build W, tile-major (NO swizzle: B is read direct-to-reg) ----
// Wt[t][j][32 bf16]: K-tile t (32 elems), row j. A (t,j) slice is 64B.
__global__ void build_w(const float* __restrict__ theta,
                        const float* __restrict__ noise,
                        __bf16* __restrict__ Wt) {
    int idx = blockIdx.x * 256 + threadIdx.x;   // 0..262143
    int j = idx >> 9;
    int d = idx & 511;
    float v;
    if (j < KDIM) v = theta[j * 512 + d];
    else          v = theta[(j - KDIM) * 512 + d] + 0.01f * noise[(j - KDIM) * 512 + d];
    Wt[((d >> 5) * 512 + j) * 32 + (d & 31)] = (__bf16)v;
}

// ---------- K1: MFMA GEMM -> packed sign bits ----------
// Tile 64(M) x 512(N), BK=32, 512 threads = 8 waves, wave-tile 64x64 (wave=wc).
// Each 64-row stripe of basis is touched by exactly ONE block (A amortized
// over all 512 cols). A: per-thread float4 -> cvt -> swizzled ds_write_b64,
// double-buffered 2x4KB LDS. B: NO LDS -- direct global->reg bf16x8 fragment
// loads from L2-resident tile-major Wt (1KB contiguous per wave per frag),
// prefetched one K-tile ahead into a double register set. One raw s_barrier
// per K-step; compiler-managed counted waits keep loads in flight across it.
__global__ void __launch_bounds__(512, 4)
gemm_signs(const float* __restrict__ basis,
           const __bf16* __restrict__ Wt,
           uint64_t* __restrict__ sbits) {
    __shared__ char smem[34816];   // K-loop: A dbuf [2][64r][64B]=8KB; epilogue [512][68]

    const int tid    = threadIdx.x;
    const int lane   = tid & 63;
    const int wc     = tid >> 6;       // wave 0..7 = column panel
    const int lane16 = lane & 15;
    const int lgrp   = lane >> 4;

    // bijective XCD swizzle: nwg=1564=8*195+4 (m204)
    const int orig = blockIdx.x;
    const int x    = orig & 7;
    const int bm   = (x < 4 ? x * 196 : 784 + (x - 4) * 195) + (orig >> 3);  // 0..1563

    // ---- A staging: 8 threads/row, 16B f32 each ----
    const int rl  = tid >> 3;          // local row 0..63
    const int oct = tid & 7;           // 16B-of-f32 (= 8B of bf16) slot
    int r = bm * 64 + rl; if (r > 99999) r = 99999;   // tail clamp (masked later)
    const float* asrc = basis + (size_t)r * 512 + oct * 4;
    const int awofs = rl * 64 + (((oct >> 1) ^ ((rl >> 1) & 3)) << 4) + ((oct & 1) << 3);

    // ---- B fragment addressing (direct global) ----
    const char* wbase = (const char*)Wt;
    int bfofs[4];
    #pragma unroll
    for (int n = 0; n < 4; ++n)
        bfofs[n] = (wc * 64 + n * 16 + lane16) * 64 + lgrp * 16;

    f32x4  acc[4][4] = {};
    float4 ra[2];                      // A(t) lives in ra[t&1]
    bf16x8 bf[2][4];                   // B(t) frags live in bf[t&1]

    // ---- prologue: A(0),A(1),B(0); write As[0]; drain own ds_writes ----
    ra[0] = *(const float4*)(asrc);
    ra[1] = *(const float4*)(asrc + 32);
    #pragma unroll
    for (int n = 0; n < 4; ++n)
        bf[0][n] = *(const bf16x8*)(wbase + bfofs[n]);
    {
        bf16x4 v;
        v[0] = (__bf16)ra[0].x; v[1] = (__bf16)ra[0].y;
        v[2] = (__bf16)ra[0].z; v[3] = (__bf16)ra[0].w;
        *(bf16x4*)(smem + awofs) = v;
    }
    asm volatile("s_waitcnt lgkmcnt(0)" ::: "memory");   // writes visible pre-barrier

    #pragma unroll
    for (int t = 0; t < 16; ++t) {
        // issue next-tile loads; they stay in flight across the barrier
        if (t < 14) ra[t & 1] = *(const float4*)(asrc + (t + 2) * 32);
        if (t < 15) {
            #pragma unroll
            for (int n = 0; n < 4; ++n)
                bf[(t + 1) & 1][n] =
                    *(const bf16x8*)(wbase + (size_t)(t + 1) * 32768 + bfofs[n]);
        }

        __builtin_amdgcn_s_barrier();   // A(t) writes visible; A(t+1) buf free

        // cvt + write A(t+1) into the opposite-parity buffer
        if (t < 15) {
            bf16x4 v;
            float4 rv = ra[(t + 1) & 1];
            v[0] = (__bf16)rv.x; v[1] = (__bf16)rv.y;
            v[2] = (__bf16)rv.z; v[3] = (__bf16)rv.w;
            *(bf16x4*)(smem + (((t + 1) & 1) << 12) + awofs) = v;
        }

        const char* ab = smem + ((t & 1) << 12);
        #pragma unroll
        for (int mh = 0; mh < 2; ++mh) {
            bf16x8 af[2];
            #pragma unroll
            for (int mi = 0; mi < 2; ++mi) {
                int rr = (mh * 2 + mi) * 16 + lane16;
                af[mi] = *(const bf16x8*)(ab + rr * 64
                           + ((lgrp ^ ((rr >> 1) & 3)) << 4));
            }
            asm volatile("s_waitcnt lgkmcnt(0)" ::: "memory");
            __builtin_amdgcn_sched_barrier(0);
            __builtin_amdgcn_s_setprio(1);
            #pragma unroll
            for (int mi = 0; mi < 2; ++mi)
                #pragma unroll
                for (int n = 0; n < 4; ++n)
                    acc[mh * 2 + mi][n] = __builtin_amdgcn_mfma_f32_16x16x32_bf16(
                        af[mi], bf[t & 1][n], acc[mh * 2 + mi][n], 0, 0, 0);
            __builtin_amdgcn_s_setprio(0);
        }
    }

    // ---- epilogue: sign bytes -> LDS transpose -> multiply-pack -> u64 ----
    // C/D layout: col = lane&15, row = (lane>>4)*4 + reg
    __builtin_amdgcn_s_barrier();                 // done with K-loop LDS
    unsigned char* sb = (unsigned char*)smem;     // [512 cols][68B] = 34.8KB
    #pragma unroll
    for (int m = 0; m < 4; ++m) {
        #pragma unroll
        for (int n = 0; n < 4; ++n) {
            int cc = wc * 64 + n * 16 + lane16;   // col 0..511
            int rb = m * 16 + lgrp * 4;           // row base 0..60
            uint32_t pk = 0;
            #pragma unroll
            for (int rg = 0; rg < 4; ++rg)
                pk |= (acc[m][n][rg] < 0.0f ? 1u : 0u) << (8 * rg);
            *(uint32_t*)&sb[cc * 68 + rb] = pk;
        }
    }
    asm volatile("s_waitcnt lgkmcnt(0)" ::: "memory");
    __builtin_amdgcn_s_barrier();

    {   // one thread per column; 64 sign bytes -> u64; word index = bm
        const unsigned char* src = &sb[tid * 68];
        uint64_t wbits = 0;
        #pragma unroll
        for (int k = 0; k < 16; ++k) {
            uint32_t qv = *(const uint32_t*)&src[4 * k];
            uint32_t p4 = ((qv & 0x01010101u) * 0x10204080u) >> 28;
            wbits |= (uint64_t)p4 << (4 * k);
        }
        sbits[(size_t)bm * 512 + tid] = wbits;    // 4KB contiguous per block
    }
}

// ---------- K2: crossing masks from sign bits ----------
__global__ void crossing_masks(const uint64_t* __restrict__ sbits,
                               uint64_t* __restrict__ maskT) {
    const int w = blockIdx.x;       // 0..1562
    const int j = threadIdx.x;      // 0..255
    uint64_t s0r = sbits[(size_t)w * 512 + j];
    uint64_t s0p = sbits[(size_t)w * 512 + 256 + j];
    uint64_t s1r = sbits[(size_t)(w + 1) * 512 + j];
    uint64_t s1p = sbits[(size_t)(w + 1) * 512 + 256 + j];
    uint64_t cr = s0r ^ ((s0r >> 1) | (s1r << 63));
    uint64_t cp = s0p ^ ((s0p >> 1) | (s1p << 63));
    uint64_t m = cr & cp;
    if (w == NW - 1) m &= 0x7FFFFFFFull;    // 31 valid crossings in last word
    maskT[(size_t)w * 256 + j] = m;
}

// ---------- K3: pairwise AND-popcount ----------
__global__ void zero_out(float* __restrict__ out) {
    int i = blockIdx.x * 256 + threadIdx.x;
    if (i < 32640) out[i] = 0.0f;
}

__global__ void pair_popcount(const uint64_t* __restrict__ maskT,
                              float* __restrict__ out) {
    const int i = blockIdx.x;   // 0..255
    const int c = blockIdx.y;   // 0..7 word chunk
    const int j = threadIdx.x;  // 0..255
    if (j <= i) return;
    int w0 = c * 196;
    int w1 = w0 + 196; if (w1 > NW) w1 = NW;
    uint32_t sum = 0;
    #pragma unroll 4
    for (int w = w0; w < w1; ++w) {
        uint64_t mi = maskT[(size_t)w * 256 + i];   // block-uniform -> scalar
        uint64_t mj = maskT[(size_t)w * 256 + j];   // coalesced
        sum += (uint32_t)__popcll(mi & mj);
    }
    const size_t idx = (size_t)i * (2 * KDIM - i - 1) / 2 + (size_t)(j - i - 1);
    atomicAdd(&out[idx], (float)sum);   // exact-integer f32 adds -> deterministic
}

extern "C" void kernel_launch(void* const* d_in, const int* in_sizes, int n_in,
                              void* d_out, int out_size, void* d_ws, size_t ws_size,
                              hipStream_t stream) {
    const float* theta = (const float*)d_in[0];
    const float* basis = (const float*)d_in[1];
    const float* noise = (const float*)d_in[2];
    float* out = (float*)d_out;

    char* ws = (char*)d_ws;
    __bf16*   Wt    = (__bf16*)ws;                              // 512 KB, tile-major
    uint64_t* sbits = (uint64_t*)(ws + 524288);                 // 1564*512*8 = 6.41 MB
    uint64_t* maskT = (uint64_t*)(ws + 524288 + (size_t)NWORDS * 512 * 8); // 3.2 MB

    hipLaunchKernelGGL(build_w,        dim3(1024),    dim3(256), 0, stream, theta, noise, Wt);
    hipLaunchKernelGGL(gemm_signs,     dim3(NWORDS),  dim3(512), 0, stream, basis, Wt, sbits);
    hipLaunchKernelGGL(crossing_masks, dim3(NW),      dim3(256), 0, stream, sbits, maskT);
    hipLaunchKernelGGL(zero_out,       dim3(128),     dim3(256), 0, stream, out);
    hipLaunchKernelGGL(pair_popcount,  dim3(KDIM, 8), dim3(256), 0, stream, maskT, out);
}